// Round 1
// baseline (994.749 us; speedup 1.0000x reference)
//
#include <hip/hip_runtime.h>
#include <stdint.h>
#include <stddef.h>

#define BB 16
#define LL 512
#define HIDD 1024
#define NHH 16
#define HDD 64
#define DQK 192   // 3*HD concatenated q/k feature dim

typedef __attribute__((ext_vector_type(8))) short bf16x8;
typedef __attribute__((ext_vector_type(4))) float f32x4;

__device__ __forceinline__ unsigned short f2bf(float f) {
  unsigned u = __builtin_bit_cast(unsigned, f);
  u += 0x7fffu + ((u >> 16) & 1u);   // RNE; inputs finite
  return (unsigned short)(u >> 16);
}

// ---------------- weight transpose: fp32 [1024][1024] -> bf16 [1024][1024]^T --
struct TransArgs { const float* in[8]; unsigned short* out[8]; };

__global__ __launch_bounds__(256) void wtrans_k(TransArgs a) {
  __shared__ unsigned short t[32][33];
  const float* in = a.in[blockIdx.z];
  unsigned short* out = a.out[blockIdx.z];
  const int tx = threadIdx.x, ty = threadIdx.y;
  const int x = blockIdx.x * 32 + tx;
  #pragma unroll
  for (int i = ty; i < 32; i += 8)
    t[i][tx] = f2bf(in[(size_t)(blockIdx.y * 32 + i) * 1024 + x]);
  __syncthreads();
  const int xo = blockIdx.y * 32 + tx;
  #pragma unroll
  for (int i = ty; i < 32; i += 8)
    out[(size_t)(blockIdx.x * 32 + i) * 1024 + xo] = t[tx][i];
}

// ---------------- generic GEMM: C = A[8192x1024] * Bt[1024x1024]^T + bias -----
// Output element (row=token, col=c) goes to:
//   addr = (tok>>9)*sB + (c>>6)*sH + (tok&511)*sL + (c&63)*sD + obase
// A_F32: A is fp32 (convert to bf16 while staging); else A is bf16 (ushort).
// OUT_F32: write float; else write bf16 (ushort).
template<int A_F32, int OUT_F32>
__global__ __launch_bounds__(256) void gemm_k(
    const void* __restrict__ Ap, const unsigned short* __restrict__ Bt,
    const float* __restrict__ bias, void* __restrict__ Cp,
    int sB, int sH, int sL, int sD, int obase)
{
  // LDS tiles 128x64 bf16, XOR-swizzled (byte ^= (row&7)<<4) -> conflict-free b128
  __shared__ unsigned short As[128 * 64];
  __shared__ unsigned short Bs[128 * 64];
  const int tid = threadIdx.x;
  const int m0 = blockIdx.y * 128, n0 = blockIdx.x * 128;
  const int w = tid >> 6, l = tid & 63;
  const int lr = l & 15, lg = l >> 4;
  const int wr = (w >> 1) * 64, wc = (w & 1) * 64;
  const int srow = tid >> 3, schunk = tid & 7;   // stage: 32 rows/pass, 8 chunks of 16B

  f32x4 acc[4][4];
  #pragma unroll
  for (int i = 0; i < 4; ++i)
    #pragma unroll
    for (int j = 0; j < 4; ++j) acc[i][j] = (f32x4){0.f, 0.f, 0.f, 0.f};

  for (int k0 = 0; k0 < 1024; k0 += 64) {
    #pragma unroll
    for (int p = 0; p < 4; ++p) {
      const int r = p * 32 + srow;
      const unsigned dst = (unsigned)(r * 128 + ((schunk * 16) ^ ((r & 7) << 4)));
      if (A_F32) {
        const float* Af = (const float*)Ap;
        const float4* src = (const float4*)(Af + (size_t)(m0 + r) * 1024 + k0 + schunk * 8);
        float4 v0 = src[0], v1 = src[1];
        union { bf16x8 v; unsigned short u[8]; } bb;
        bb.u[0] = f2bf(v0.x); bb.u[1] = f2bf(v0.y); bb.u[2] = f2bf(v0.z); bb.u[3] = f2bf(v0.w);
        bb.u[4] = f2bf(v1.x); bb.u[5] = f2bf(v1.y); bb.u[6] = f2bf(v1.z); bb.u[7] = f2bf(v1.w);
        *(bf16x8*)((char*)As + dst) = bb.v;
      } else {
        const unsigned short* Ab = (const unsigned short*)Ap;
        *(bf16x8*)((char*)As + dst) = *(const bf16x8*)(Ab + (size_t)(m0 + r) * 1024 + k0 + schunk * 8);
      }
      *(bf16x8*)((char*)Bs + dst) = *(const bf16x8*)(Bt + (size_t)(n0 + r) * 1024 + k0 + schunk * 8);
    }
    __syncthreads();
    #pragma unroll
    for (int kk = 0; kk < 64; kk += 32) {
      bf16x8 af[4], bfr[4];
      #pragma unroll
      for (int i = 0; i < 4; ++i) {
        const int ar = wr + i * 16 + lr;
        af[i] = *(const bf16x8*)((const char*)As + ar * 128 + (((kk + lg * 8) * 2) ^ ((ar & 7) << 4)));
      }
      #pragma unroll
      for (int j = 0; j < 4; ++j) {
        const int br = wc + j * 16 + lr;
        bfr[j] = *(const bf16x8*)((const char*)Bs + br * 128 + (((kk + lg * 8) * 2) ^ ((br & 7) << 4)));
      }
      #pragma unroll
      for (int i = 0; i < 4; ++i)
        #pragma unroll
        for (int j = 0; j < 4; ++j)
          acc[i][j] = __builtin_amdgcn_mfma_f32_16x16x32_bf16(af[i], bfr[j], acc[i][j], 0, 0, 0);
    }
    __syncthreads();
  }
  // epilogue
  #pragma unroll
  for (int j = 0; j < 4; ++j) {
    const int col = n0 + wc + j * 16 + lr;
    const float bv = bias[col];
    #pragma unroll
    for (int i = 0; i < 4; ++i) {
      #pragma unroll
      for (int r = 0; r < 4; ++r) {
        const int row = m0 + wr + i * 16 + lg * 4 + r;
        const float val = acc[i][j][r] + bv;
        const size_t addr = (size_t)(row >> 9) * sB + (size_t)(col >> 6) * sH
                          + (size_t)(row & 511) * sL + (size_t)(col & 63) * sD + obase;
        if (OUT_F32) ((float*)Cp)[addr] = val;
        else         ((unsigned short*)Cp)[addr] = f2bf(val);
      }
    }
  }
}

// ---------------- fused causal attention with additive relative_time ---------
// Q,K: [BH][L][192] bf16; Vt: [BH][64][L] bf16; rt: [BH][L][L] fp32;
// O: [B][L][HID] bf16 (token-major for the final projection).
__global__ __launch_bounds__(256) void attn_k(
    const unsigned short* __restrict__ Q, const unsigned short* __restrict__ Kc,
    const unsigned short* __restrict__ Vt, const float* __restrict__ rt,
    unsigned short* __restrict__ O)
{
  __shared__ unsigned short K_lds[64 * 192];  // row stride 384B, swizzled
  __shared__ unsigned short V_lds[64 * 64];   // [d][kv], row stride 128B, swizzled
  __shared__ unsigned short P_lds[128 * 64];  // row stride 128B, swizzled
  const int tid = threadIdx.x;
  const int w = tid >> 6, l = tid & 63, lr = l & 15, lg = l >> 4;
  const int bh = blockIdx.y, qt = blockIdx.x;
  const int q0 = qt * 128;
  const int qw = q0 + w * 32;          // this wave's first q row

  const unsigned short* Qb = Q + (size_t)bh * LL * DQK;
  const unsigned short* Kb = Kc + (size_t)bh * LL * DQK;
  const unsigned short* Vb = Vt + (size_t)bh * HDD * LL;
  const float* rtb = rt + (size_t)bh * LL * LL;

  // Q fragments hoisted to registers: [rowblk 0..1][kchunk 0..5]
  bf16x8 qf[2][6];
  #pragma unroll
  for (int rb = 0; rb < 2; ++rb) {
    const int qrow = qw + rb * 16 + lr;
    #pragma unroll
    for (int kc = 0; kc < 6; ++kc)
      qf[rb][kc] = *(const bf16x8*)(Qb + (size_t)qrow * DQK + kc * 32 + lg * 8);
  }

  f32x4 accO[2][4];
  float m_s[2][4], l_s[2][4];
  #pragma unroll
  for (int rb = 0; rb < 2; ++rb) {
    #pragma unroll
    for (int d = 0; d < 4; ++d) accO[rb][d] = (f32x4){0.f, 0.f, 0.f, 0.f};
    #pragma unroll
    for (int r = 0; r < 4; ++r) { m_s[rb][r] = -INFINITY; l_s[rb][r] = 0.f; }
  }

  const int nsteps = 2 * qt + 2;
  for (int s = 0; s < nsteps; ++s) {
    const int k0 = s * 64;
    // stage K tile: 64 rows x 192 bf16 = 1536 x 16B chunks
    for (int c = tid; c < 1536; c += 256) {
      const int row = c / 24, sl = c - row * 24;
      *(bf16x8*)((char*)K_lds + row * 384 + ((sl * 16) ^ ((row & 7) << 4))) =
          *(const bf16x8*)(Kb + (size_t)(k0 + row) * DQK + sl * 8);
    }
    // stage V^T tile: 64 d-rows x 64 kv
    #pragma unroll
    for (int p = 0; p < 2; ++p) {
      const int c = p * 256 + tid;
      const int row = c >> 3, sl = c & 7;
      *(bf16x8*)((char*)V_lds + row * 128 + ((sl * 16) ^ ((row & 7) << 4))) =
          *(const bf16x8*)(Vb + (size_t)row * LL + k0 + sl * 8);
    }
    __syncthreads();

    // S = Q K^T  (D=192 -> 6 mfma per 16x16 tile)
    float sc_[2][4][4];
    #pragma unroll
    for (int cb = 0; cb < 4; ++cb) {
      bf16x8 kf[6];
      const int krow = cb * 16 + lr;
      #pragma unroll
      for (int kc = 0; kc < 6; ++kc)
        kf[kc] = *(const bf16x8*)((const char*)K_lds + krow * 384 +
                                  (((kc * 32 + lg * 8) * 2) ^ ((krow & 7) << 4)));
      #pragma unroll
      for (int rb = 0; rb < 2; ++rb) {
        f32x4 a = (f32x4){0.f, 0.f, 0.f, 0.f};
        #pragma unroll
        for (int kc = 0; kc < 6; ++kc)
          a = __builtin_amdgcn_mfma_f32_16x16x32_bf16(qf[rb][kc], kf[kc], a, 0, 0, 0);
        #pragma unroll
        for (int r = 0; r < 4; ++r) sc_[rb][cb][r] = a[r];
      }
    }

    // scale + relative_time + causal mask
    const bool dstep = (s >= 2 * qt);   // only the last two steps touch the diagonal
    #pragma unroll
    for (int rb = 0; rb < 2; ++rb)
      #pragma unroll
      for (int cb = 0; cb < 4; ++cb) {
        const int k = k0 + cb * 16 + lr;
        #pragma unroll
        for (int r = 0; r < 4; ++r) {
          const int q = qw + rb * 16 + lg * 4 + r;
          float v = sc_[rb][cb][r] * 0.125f + rtb[(size_t)q * LL + k];
          if (dstep && k > q) v = -INFINITY;
          sc_[rb][cb][r] = v;
        }
      }

    // online softmax (row = lg*4+r; reduce over the 16 lanes holding the columns)
    #pragma unroll
    for (int rb = 0; rb < 2; ++rb)
      #pragma unroll
      for (int r = 0; r < 4; ++r) {
        float mx = fmaxf(fmaxf(sc_[rb][0][r], sc_[rb][1][r]), fmaxf(sc_[rb][2][r], sc_[rb][3][r]));
        mx = fmaxf(mx, __shfl_xor(mx, 1, 64));
        mx = fmaxf(mx, __shfl_xor(mx, 2, 64));
        mx = fmaxf(mx, __shfl_xor(mx, 4, 64));
        mx = fmaxf(mx, __shfl_xor(mx, 8, 64));
        const float mo = m_s[rb][r];
        const float mn = fmaxf(mo, mx);
        const float alpha = exp2f((mo - mn) * 1.4426950408889634f);
        float psum = 0.f;
        #pragma unroll
        for (int cb = 0; cb < 4; ++cb) {
          const float p = exp2f((sc_[rb][cb][r] - mn) * 1.4426950408889634f);
          sc_[rb][cb][r] = p;
          psum += p;
        }
        psum += __shfl_xor(psum, 1, 64);
        psum += __shfl_xor(psum, 2, 64);
        psum += __shfl_xor(psum, 4, 64);
        psum += __shfl_xor(psum, 8, 64);
        l_s[rb][r] = l_s[rb][r] * alpha + psum;
        m_s[rb][r] = mn;
        #pragma unroll
        for (int d = 0; d < 4; ++d) accO[rb][d][r] *= alpha;
      }

    // P -> LDS (rows are wave-private; no barrier needed, compiler orders LDS deps)
    #pragma unroll
    for (int rb = 0; rb < 2; ++rb)
      #pragma unroll
      for (int cb = 0; cb < 4; ++cb)
        #pragma unroll
        for (int r = 0; r < 4; ++r) {
          const int prow = w * 32 + rb * 16 + lg * 4 + r;
          const int pcol = cb * 16 + lr;
          *(unsigned short*)((char*)P_lds + prow * 128 + ((pcol * 2) ^ ((prow & 7) << 4))) =
              f2bf(sc_[rb][cb][r]);
        }

    // O += P V
    #pragma unroll
    for (int kk = 0; kk < 2; ++kk) {
      bf16x8 pf[2];
      #pragma unroll
      for (int rb = 0; rb < 2; ++rb) {
        const int prow = w * 32 + rb * 16 + lr;
        pf[rb] = *(const bf16x8*)((const char*)P_lds + prow * 128 +
                                  (((kk * 32 + lg * 8) * 2) ^ ((prow & 7) << 4)));
      }
      #pragma unroll
      for (int d = 0; d < 4; ++d) {
        const int vrow = d * 16 + lr;
        const bf16x8 vf = *(const bf16x8*)((const char*)V_lds + vrow * 128 +
                                           (((kk * 32 + lg * 8) * 2) ^ ((vrow & 7) << 4)));
        #pragma unroll
        for (int rb = 0; rb < 2; ++rb)
          accO[rb][d] = __builtin_amdgcn_mfma_f32_16x16x32_bf16(pf[rb], vf, accO[rb][d], 0, 0, 0);
      }
    }
    __syncthreads();
  }

  // epilogue: O[b][q][h*64+d] = accO / l
  const int b = bh >> 4, h = bh & 15;
  #pragma unroll
  for (int rb = 0; rb < 2; ++rb)
    #pragma unroll
    for (int d = 0; d < 4; ++d)
      #pragma unroll
      for (int r = 0; r < 4; ++r) {
        const int q = qw + rb * 16 + lg * 4 + r;
        const int dd = d * 16 + lr;
        const float o = accO[rb][d][r] / l_s[rb][r];
        O[(size_t)(b * 512 + q) * 1024 + h * 64 + dd] = f2bf(o);
      }
}

// -----------------------------------------------------------------------------
extern "C" void kernel_launch(void* const* d_in, const int* in_sizes, int n_in,
                              void* d_out, int out_size, void* d_ws, size_t ws_size,
                              hipStream_t stream) {
  const float* seq_id   = (const float*)d_in[0];
  const float* seq_cate = (const float*)d_in[1];
  const float* seq_pos  = (const float*)d_in[2];
  const float* V_id     = (const float*)d_in[3];
  // d_in[4] = attn_mask (deterministic causal tril) — not read
  const float* rt       = (const float*)d_in[5];
  const float* q_id_w   = (const float*)d_in[6];
  const float* q_id_b   = (const float*)d_in[7];
  const float* k_id_w   = (const float*)d_in[8];
  const float* k_id_b   = (const float*)d_in[9];
  const float* v_id_w   = (const float*)d_in[10];
  const float* v_id_b   = (const float*)d_in[11];
  const float* q_cate_w = (const float*)d_in[12];
  const float* q_cate_b = (const float*)d_in[13];
  const float* k_cate_w = (const float*)d_in[14];
  const float* k_cate_b = (const float*)d_in[15];
  const float* q_pos_w  = (const float*)d_in[16];
  const float* q_pos_b  = (const float*)d_in[17];
  const float* k_pos_w  = (const float*)d_in[18];
  const float* k_pos_b  = (const float*)d_in[19];
  const float* out_w    = (const float*)d_in[20];
  const float* out_b    = (const float*)d_in[21];

  // workspace layout (bf16 elements)
  unsigned short* wt = (unsigned short*)d_ws;               // 8 x 1024*1024
  unsigned short* Qw = wt + (size_t)8 * 1048576;            // [BH][L][192]
  unsigned short* Kw = Qw + (size_t)25165824;
  unsigned short* Vw = Kw + (size_t)25165824;               // [BH][64][L]
  unsigned short* Ow = Vw + (size_t)8388608;                // [B][L][HID]

  TransArgs ta;
  ta.in[0] = q_id_w;   ta.in[1] = k_id_w;   ta.in[2] = v_id_w;  ta.in[3] = q_cate_w;
  ta.in[4] = k_cate_w; ta.in[5] = q_pos_w;  ta.in[6] = k_pos_w; ta.in[7] = out_w;
  for (int i = 0; i < 8; ++i) ta.out[i] = wt + (size_t)i * 1048576;
  wtrans_k<<<dim3(32, 32, 8), dim3(32, 8), 0, stream>>>(ta);

  const dim3 gg(8, 64), gb(256);
  const int QsB = NHH * LL * DQK, QsH = LL * DQK;
  // Qcat / Kcat / V^T projections
  gemm_k<1, 0><<<gg, gb, 0, stream>>>(seq_id,   wt + (size_t)0 * 1048576, q_id_b,   Qw, QsB, QsH, DQK, 1, 0);
  gemm_k<1, 0><<<gg, gb, 0, stream>>>(seq_id,   wt + (size_t)1 * 1048576, k_id_b,   Kw, QsB, QsH, DQK, 1, 0);
  gemm_k<1, 0><<<gg, gb, 0, stream>>>(V_id,     wt + (size_t)2 * 1048576, v_id_b,   Vw, NHH * HDD * LL, HDD * LL, 1, LL, 0);
  gemm_k<1, 0><<<gg, gb, 0, stream>>>(seq_cate, wt + (size_t)3 * 1048576, q_cate_b, Qw, QsB, QsH, DQK, 1, 64);
  gemm_k<1, 0><<<gg, gb, 0, stream>>>(seq_cate, wt + (size_t)4 * 1048576, k_cate_b, Kw, QsB, QsH, DQK, 1, 64);
  gemm_k<1, 0><<<gg, gb, 0, stream>>>(seq_pos,  wt + (size_t)5 * 1048576, q_pos_b,  Qw, QsB, QsH, DQK, 1, 128);
  gemm_k<1, 0><<<gg, gb, 0, stream>>>(seq_pos,  wt + (size_t)6 * 1048576, k_pos_b,  Kw, QsB, QsH, DQK, 1, 128);

  attn_k<<<dim3(4, 256), 256, 0, stream>>>(Qw, Kw, Vw, rt, Ow);

  // out = O @ out_w + out_b  -> fp32 d_out (token-major linear)
  gemm_k<0, 1><<<gg, gb, 0, stream>>>(Ow, wt + (size_t)7 * 1048576, out_b, d_out, LL * HIDD, 64, HIDD, 1, 0);
}